// Round 1
// baseline (438.432 us; speedup 1.0000x reference)
//
#include <hip/hip_runtime.h>
#include <hip/hip_bf16.h>
#include <cstdint>

#define NND 100000
#define NED 1600000
#define FIN 128
#define FOUT 64

// bucket-sort CSR parameters
#define NBLK 512              // histogram/scatter blocks
#define EPB (NED / NBLK)      // 3125 edges per block (exact)
#define NBUCK 256             // coarse buckets
#define BSH 9                 // bucket = dst >> 9
#define BNODES 512            // nodes per bucket
#define HTN (NBUCK * NBLK)    // histT length = 131072

typedef __bf16 bf16x8 __attribute__((ext_vector_type(8)));
typedef float f32x4 __attribute__((ext_vector_type(4)));

static __device__ inline unsigned short f2bf(float f) {
    unsigned int u = __builtin_bit_cast(unsigned int, f);
    unsigned int r = (u + 0x7fffu + ((u >> 16) & 1u)) >> 16;  // RNE
    return (unsigned short)r;
}
static __device__ inline float bflo(unsigned int v) {
    return __builtin_bit_cast(float, v << 16);
}
static __device__ inline float bfhi(unsigned int v) {
    return __builtin_bit_cast(float, v & 0xffff0000u);
}
static __device__ inline float bf1(unsigned short u) {
    return __builtin_bit_cast(float, (unsigned int)u << 16);
}

// ---------------- weight pack into MFMA B-fragment order ----------------
static __device__ inline void pack_one(const float* __restrict__ W,
                                       unsigned short* __restrict__ out,
                                       int NTtot, int c_local, int nt,
                                       int chunkOff, int ncols, int lane) {
    int k = c_local * 32 + (lane >> 4) * 8;
    int n = nt * 16 + (lane & 15);
    unsigned short t[8];
#pragma unroll
    for (int j = 0; j < 8; j++) t[j] = f2bf(W[(size_t)(k + j) * ncols + n]);
    uint4 u;
    u.x = t[0] | ((unsigned)t[1] << 16);
    u.y = t[2] | ((unsigned)t[3] << 16);
    u.z = t[4] | ((unsigned)t[5] << 16);
    u.w = t[6] | ((unsigned)t[7] << 16);
    *(uint4*)&out[((size_t)((c_local + chunkOff) * NTtot + nt) * 64 + lane) * 8] = u;
}

// ---------------- K1: per-block bucket histogram + x cast + weight pack ----
__global__ __launch_bounds__(256) void k_hist_cast(
        const int* __restrict__ dst, int* __restrict__ histT,
        const float* __restrict__ x, unsigned int* __restrict__ xb,
        const float* W1l, const float* W1r, const float* W2l,
        const float* W2r, const float* Wlin,
        unsigned short* p1, unsigned short* p2, unsigned short* ph) {
    __shared__ int hist[NBUCK];
    const int tid = threadIdx.x, blk = blockIdx.x;
    hist[tid] = 0;  // 256 threads == NBUCK
    __syncthreads();
    const int e0 = blk * EPB, e1 = e0 + EPB;
    for (int i = e0 + tid; i < e1; i += 256)
        atomicAdd(&hist[dst[i] >> BSH], 1);   // LDS atomic
    __syncthreads();
    histT[tid * NBLK + blk] = hist[tid];
    // fused weight pack (blocks 0..143, first wave)
    if (blk < 144 && tid < 64) {
        int b = blk, lane = tid;
        if (b < 32)       pack_one(W1l, p1, 8, b >> 3, b & 7, 0, 128, lane);
        else if (b < 64)  { b -= 32; pack_one(W1r, p1, 8, b >> 3, b & 7, 4, 128, lane); }
        else if (b < 96)  { b -= 64; pack_one(W2l, p2, 8, b >> 3, b & 7, 0, 128, lane); }
        else if (b < 128) { b -= 96; pack_one(W2r, p2, 8, b >> 3, b & 7, 4, 128, lane); }
        else              { b -= 128; pack_one(Wlin, ph, 4, b >> 2, b & 3, 0, 64, lane); }
    }
    // fused cast: grid-stride over N*32 float4
    const int total4 = NND * 32;
    for (int i = blk * 256 + tid; i < total4; i += NBLK * 256) {
        float4 v = ((const float4*)x)[i];
        uint2 o;
        o.x = (unsigned)f2bf(v.x) | ((unsigned)f2bf(v.y) << 16);
        o.y = (unsigned)f2bf(v.z) | ((unsigned)f2bf(v.w) << 16);
        ((uint2*)xb)[i] = o;
    }
}

// ---------------- generic hierarchical exclusive scan (n = HTN) ------------
__global__ __launch_bounds__(1024) void g_scan1(const int* __restrict__ in,
                                                int* __restrict__ psum, int n) {
    __shared__ int red[1024];
    int tid = threadIdx.x;
    int i = blockIdx.x * 1024 + tid;
    red[tid] = (i < n) ? in[i] : 0;
    __syncthreads();
#pragma unroll
    for (int off = 512; off > 0; off >>= 1) {
        if (tid < off) red[tid] += red[tid + off];
        __syncthreads();
    }
    if (tid == 0) psum[blockIdx.x] = red[0];
}

__global__ __launch_bounds__(128) void g_scan2(int* __restrict__ psum, int nb) {
    int tid = threadIdx.x;
    int d = (tid < nb) ? psum[tid] : 0;
    int v = d;
#pragma unroll
    for (int off = 1; off < 64; off <<= 1) {
        int u = __shfl_up(v, off, 64);
        if ((tid & 63) >= off) v += u;
    }
    __shared__ int ws[2];
    if ((tid & 63) == 63) ws[tid >> 6] = v;
    __syncthreads();
    int base = (tid >= 64) ? ws[0] : 0;
    if (tid < nb) psum[tid] = base + v - d;
}

__global__ __launch_bounds__(1024) void g_scan3(const int* __restrict__ in,
                                                const int* __restrict__ psum,
                                                int* __restrict__ out, int n) {
    int tid = threadIdx.x;
    int i = blockIdx.x * 1024 + tid;
    int d = (i < n) ? in[i] : 0;
    int v = d;
#pragma unroll
    for (int off = 1; off < 64; off <<= 1) {
        int u = __shfl_up(v, off, 64);
        if ((tid & 63) >= off) v += u;
    }
    __shared__ int wsum[16];
    int wid = tid >> 6;
    if ((tid & 63) == 63) wsum[wid] = v;
    __syncthreads();
    if (tid < 16) {
        int w = wsum[tid];
#pragma unroll
        for (int off = 1; off < 16; off <<= 1) {
            int u = __shfl_up(w, off, 64);
            if (tid >= off) w += u;
        }
        wsum[tid] = w;
    }
    __syncthreads();
    int base = psum[blockIdx.x] + (wid ? wsum[wid - 1] : 0);
    if (i < n) out[i] = base + v - d;
}

// ---------------- K3: coarse scatter into bucket-grouped pairs -------------
__global__ __launch_bounds__(256) void k_scatter(const int* __restrict__ src,
                                                 const int* __restrict__ dst,
                                                 const int* __restrict__ sh,
                                                 uint2* __restrict__ eS) {
    __shared__ int cur[NBUCK];
    const int tid = threadIdx.x, blk = blockIdx.x;
    cur[tid] = sh[tid * NBLK + blk];
    __syncthreads();
    const int e0 = blk * EPB, e1 = e0 + EPB;
    for (int i = e0 + tid; i < e1; i += 256) {
        int d = dst[i];
        int pos = atomicAdd(&cur[d >> BSH], 1);   // LDS atomic
        eS[pos] = make_uint2((unsigned)src[i], (unsigned)(d & (BNODES - 1)));
    }
}

// ---------------- K4: per-bucket counting sort -> csr, offs, dinv ----------
__global__ __launch_bounds__(1024) void k_bucket(const uint2* __restrict__ eS,
                                                 const int* __restrict__ sh,
                                                 int* __restrict__ csr,
                                                 int* __restrict__ offs,
                                                 float* __restrict__ dinv, int n) {
    __shared__ int cnt[BNODES];
    __shared__ int loc[BNODES];
    const int b = blockIdx.x, tid = threadIdx.x;
    const int base = sh[b * NBLK];
    const int end = (b == NBUCK - 1) ? NED : sh[(b + 1) * NBLK];
    if (tid < BNODES) cnt[tid] = 0;
    __syncthreads();
    for (int i = base + tid; i < end; i += 1024)
        atomicAdd(&cnt[eS[i].y], 1);              // LDS atomic
    __syncthreads();
    // inclusive Hillis-Steele scan of cnt -> loc
    if (tid < BNODES) loc[tid] = cnt[tid];
    __syncthreads();
#pragma unroll
    for (int off = 1; off < BNODES; off <<= 1) {
        int v = 0;
        if (tid < BNODES && tid >= off) v = loc[tid - off];
        __syncthreads();
        if (tid < BNODES) loc[tid] += v;
        __syncthreads();
    }
    int node = b * BNODES + tid;
    int myExcl = 0;
    if (tid < BNODES) {
        myExcl = loc[tid] - cnt[tid];  // exclusive
        if (node < n) {
            offs[node] = base + myExcl;
            dinv[node] = 1.0f / fmaxf((float)cnt[tid], 1.0f);
        }
    }
    __syncthreads();
    if (tid < BNODES) cnt[tid] = base + myExcl;  // running cursor
    __syncthreads();
    for (int i = base + tid; i < end; i += 1024) {
        uint2 e = eS[i];
        int slot = atomicAdd(&cnt[e.y], 1);       // LDS atomic
        csr[slot] = (int)e.x;
    }
    if (b == 0 && tid == 0) offs[n] = NED;
}

// ---------------- mean-aggregate: wave handles TWO nodes -------------------
// 8 independent 256B gathers in flight per wave (vs 4 before): latency/MLP fix.
#define ACCP(A, v) do { \
    A[0].x += bflo((v).x); A[0].y += bfhi((v).x); \
    A[1].x += bflo((v).y); A[1].y += bfhi((v).y); \
    A[2].x += bflo((v).z); A[2].y += bfhi((v).z); \
    A[3].x += bflo((v).w); A[3].y += bfhi((v).w); } while (0)

__global__ __launch_bounds__(256) void k_aggb(const uint4* __restrict__ feat4,
                                              const int* __restrict__ offs,
                                              const int* __restrict__ csr,
                                              const float* __restrict__ dinv,
                                              uint4* __restrict__ out4, int n) {
    const int wid = blockIdx.x * 4 + (threadIdx.x >> 6);
    const int nodeA = wid * 2;
    if (nodeA >= n) return;
    const int nodeB = nodeA + 1;
    const bool hasB = nodeB < n;
    const int lane = threadIdx.x & 63;
    const int grp = lane >> 4;
    const int ch = lane & 15;

    const int begA = offs[nodeA];
    const int endA = offs[nodeA + 1];
    const int begB = hasB ? offs[nodeB] : 0;
    const int endB = hasB ? offs[nodeB + 1] : 0;

    float2 accA[4], accB[4];
#pragma unroll
    for (int j = 0; j < 4; j++) {
        accA[j] = make_float2(0.f, 0.f);
        accB[j] = make_float2(0.f, 0.f);
    }

    int iA = begA, iB = begB;
    const int fullA = begA + ((endA - begA) & ~15);
    const int fullB = begB + ((endB - begB) & ~15);

    // joint main: straight-line 32 edges (16 per node), 8 gathers in flight
    while (iA < fullA && iB < fullB) {
        int sa0 = csr[iA + grp], sa1 = csr[iA + 4 + grp];
        int sa2 = csr[iA + 8 + grp], sa3 = csr[iA + 12 + grp];
        int sb0 = csr[iB + grp], sb1 = csr[iB + 4 + grp];
        int sb2 = csr[iB + 8 + grp], sb3 = csr[iB + 12 + grp];
        uint4 va0 = feat4[(size_t)sa0 * 16 + ch];
        uint4 va1 = feat4[(size_t)sa1 * 16 + ch];
        uint4 va2 = feat4[(size_t)sa2 * 16 + ch];
        uint4 va3 = feat4[(size_t)sa3 * 16 + ch];
        uint4 vb0 = feat4[(size_t)sb0 * 16 + ch];
        uint4 vb1 = feat4[(size_t)sb1 * 16 + ch];
        uint4 vb2 = feat4[(size_t)sb2 * 16 + ch];
        uint4 vb3 = feat4[(size_t)sb3 * 16 + ch];
        ACCP(accA, va0); ACCP(accA, va1); ACCP(accA, va2); ACCP(accA, va3);
        ACCP(accB, vb0); ACCP(accB, vb1); ACCP(accB, vb2); ACCP(accB, vb3);
        iA += 16; iB += 16;
    }
    // drain whichever node still has full batches
    for (; iA < fullA; iA += 16) {
        int s0 = csr[iA + grp], s1 = csr[iA + 4 + grp];
        int s2 = csr[iA + 8 + grp], s3 = csr[iA + 12 + grp];
        uint4 v0 = feat4[(size_t)s0 * 16 + ch];
        uint4 v1 = feat4[(size_t)s1 * 16 + ch];
        uint4 v2 = feat4[(size_t)s2 * 16 + ch];
        uint4 v3 = feat4[(size_t)s3 * 16 + ch];
        ACCP(accA, v0); ACCP(accA, v1); ACCP(accA, v2); ACCP(accA, v3);
    }
    for (; iB < fullB; iB += 16) {
        int s0 = csr[iB + grp], s1 = csr[iB + 4 + grp];
        int s2 = csr[iB + 8 + grp], s3 = csr[iB + 12 + grp];
        uint4 v0 = feat4[(size_t)s0 * 16 + ch];
        uint4 v1 = feat4[(size_t)s1 * 16 + ch];
        uint4 v2 = feat4[(size_t)s2 * 16 + ch];
        uint4 v3 = feat4[(size_t)s3 * 16 + ch];
        ACCP(accB, v0); ACCP(accB, v1); ACCP(accB, v2); ACCP(accB, v3);
    }
    // joint tail: exec-masked loads (mask uniform per 16-lane group -> no
    // memory traffic for inactive slots); zero-filled regs make accumulation
    // unconditional and keep all 8 loads independent.
#pragma unroll
    for (int g = 0; g < 4; g++) {
        int eA = iA + g * 4 + grp;
        int eB = iB + g * 4 + grp;
        uint4 vA = make_uint4(0u, 0u, 0u, 0u);
        uint4 vB = make_uint4(0u, 0u, 0u, 0u);
        if (eA < endA) vA = feat4[(size_t)csr[eA] * 16 + ch];
        if (eB < endB) vB = feat4[(size_t)csr[eB] * 16 + ch];
        ACCP(accA, vA);
        ACCP(accB, vB);
    }
#pragma unroll
    for (int j = 0; j < 4; j++) {
        accA[j].x += __shfl_xor(accA[j].x, 16);
        accA[j].y += __shfl_xor(accA[j].y, 16);
        accA[j].x += __shfl_xor(accA[j].x, 32);
        accA[j].y += __shfl_xor(accA[j].y, 32);
        accB[j].x += __shfl_xor(accB[j].x, 16);
        accB[j].y += __shfl_xor(accB[j].y, 16);
        accB[j].x += __shfl_xor(accB[j].x, 32);
        accB[j].y += __shfl_xor(accB[j].y, 32);
    }
    if (grp == 0) {
        float di = dinv[nodeA];
        uint4 o;
        o.x = (unsigned)f2bf(accA[0].x * di) | ((unsigned)f2bf(accA[0].y * di) << 16);
        o.y = (unsigned)f2bf(accA[1].x * di) | ((unsigned)f2bf(accA[1].y * di) << 16);
        o.z = (unsigned)f2bf(accA[2].x * di) | ((unsigned)f2bf(accA[2].y * di) << 16);
        o.w = (unsigned)f2bf(accA[3].x * di) | ((unsigned)f2bf(accA[3].y * di) << 16);
        out4[(size_t)nodeA * 16 + ch] = o;
        if (hasB) {
            float d2 = dinv[nodeB];
            uint4 p;
            p.x = (unsigned)f2bf(accB[0].x * d2) | ((unsigned)f2bf(accB[0].y * d2) << 16);
            p.y = (unsigned)f2bf(accB[1].x * d2) | ((unsigned)f2bf(accB[1].y * d2) << 16);
            p.z = (unsigned)f2bf(accB[2].x * d2) | ((unsigned)f2bf(accB[2].y * d2) << 16);
            p.w = (unsigned)f2bf(accB[3].x * d2) | ((unsigned)f2bf(accB[3].y * d2) << 16);
            out4[(size_t)nodeB * 16 + ch] = p;
        }
    }
}

// ---------------- MFMA GEMM (+optional fused head) ----------------
// 128 rows/block (2 row-tiles per wave): each B fragment load feeds 2 MFMAs,
// halving packed-W refetch traffic through L1/L2.
template <int NT, int KCH, bool TWO, bool RELU, bool RESID, bool HEAD, bool OUTBF>
__global__ __launch_bounds__(256) void k_mfma(const unsigned short* __restrict__ P,
                                              const unsigned short* __restrict__ Q,
                                              const unsigned short* __restrict__ Wp,
                                              const float* __restrict__ bias,
                                              const unsigned short* __restrict__ resid,
                                              const unsigned short* __restrict__ Wp2,
                                              const float* __restrict__ bias2,
                                              void* __restrict__ outv, int n) {
    const int lane = threadIdx.x & 63;
    const int wave = threadIdx.x >> 6;
    const int quad = lane >> 4;
    const int row0 = blockIdx.x * 128 + wave * 32;
    int rA0 = row0 + (lane & 15);
    if (rA0 >= n) rA0 = n - 1;
    int rA1 = row0 + 16 + (lane & 15);
    if (rA1 >= n) rA1 = n - 1;

    f32x4 acc0[NT], acc1[NT];
#pragma unroll
    for (int t = 0; t < NT; t++) {
        acc0[t] = (f32x4){0.f, 0.f, 0.f, 0.f};
        acc1[t] = (f32x4){0.f, 0.f, 0.f, 0.f};
    }

#pragma unroll
    for (int c = 0; c < KCH; c++) {
        const unsigned short* Abase = (TWO && c >= KCH / 2) ? Q : P;
        const int kk = (TWO ? (c & (KCH / 2 - 1)) : c) * 32 + quad * 8;
        bf16x8 a0 = *(const bf16x8*)&Abase[(size_t)rA0 * 128 + kk];
        bf16x8 a1 = *(const bf16x8*)&Abase[(size_t)rA1 * 128 + kk];
#pragma unroll
        for (int t = 0; t < NT; t++) {
            bf16x8 b = *(const bf16x8*)&Wp[(size_t)((c * NT + t) * 64 + lane) * 8];
            acc0[t] = __builtin_amdgcn_mfma_f32_16x16x32_bf16(a0, b, acc0[t], 0, 0, 0);
            acc1[t] = __builtin_amdgcn_mfma_f32_16x16x32_bf16(a1, b, acc1[t], 0, 0, 0);
        }
    }

    const int col = lane & 15;
    if (!HEAD) {
#pragma unroll
        for (int t = 0; t < NT; t++) {
            float bv = bias[t * 16 + col];
#pragma unroll
            for (int h = 0; h < 2; h++) {
#pragma unroll
                for (int r = 0; r < 4; r++) {
                    int row = row0 + h * 16 + quad * 4 + r;
                    if (row < n) {
                        float v = (h ? acc1[t][r] : acc0[t][r]) + bv;
                        if (RESID) v += bf1(resid[(size_t)row * 128 + t * 16 + col]);
                        if (RELU) v = fmaxf(v, 0.f);
                        if (OUTBF)
                            ((unsigned short*)outv)[(size_t)row * (NT * 16) + t * 16 + col] = f2bf(v);
                        else
                            ((float*)outv)[(size_t)row * (NT * 16) + t * 16 + col] = v;
                    }
                }
            }
        }
    } else {
        __shared__ __align__(16) unsigned short sT[4][32 * 136];
#pragma unroll
        for (int t = 0; t < NT; t++) {
            float bv = bias[t * 16 + col];
#pragma unroll
            for (int h = 0; h < 2; h++) {
#pragma unroll
                for (int r = 0; r < 4; r++) {
                    int row = row0 + h * 16 + quad * 4 + r;
                    int rr = row < n ? row : n - 1;
                    float v = (h ? acc1[t][r] : acc0[t][r]) + bv;
                    if (RESID) v += bf1(resid[(size_t)rr * 128 + t * 16 + col]);
                    if (RELU) v = fmaxf(v, 0.f);
                    sT[wave][(h * 16 + quad * 4 + r) * 136 + t * 16 + col] = f2bf(v);
                }
            }
        }
        f32x4 hacc0[4], hacc1[4];
#pragma unroll
        for (int t = 0; t < 4; t++) {
            hacc0[t] = (f32x4){0.f, 0.f, 0.f, 0.f};
            hacc1[t] = (f32x4){0.f, 0.f, 0.f, 0.f};
        }
#pragma unroll
        for (int c = 0; c < 4; c++) {
            bf16x8 a0 = *(const bf16x8*)&sT[wave][(lane & 15) * 136 + c * 32 + quad * 8];
            bf16x8 a1 = *(const bf16x8*)&sT[wave][((lane & 15) + 16) * 136 + c * 32 + quad * 8];
#pragma unroll
            for (int t = 0; t < 4; t++) {
                bf16x8 b = *(const bf16x8*)&Wp2[(size_t)((c * 4 + t) * 64 + lane) * 8];
                hacc0[t] = __builtin_amdgcn_mfma_f32_16x16x32_bf16(a0, b, hacc0[t], 0, 0, 0);
                hacc1[t] = __builtin_amdgcn_mfma_f32_16x16x32_bf16(a1, b, hacc1[t], 0, 0, 0);
            }
        }
#pragma unroll
        for (int t = 0; t < 4; t++) {
            float bv = bias2[t * 16 + col];
#pragma unroll
            for (int h = 0; h < 2; h++) {
#pragma unroll
                for (int r = 0; r < 4; r++) {
                    int row = row0 + h * 16 + quad * 4 + r;
                    if (row < n)
                        ((float*)outv)[(size_t)row * 64 + t * 16 + col] =
                            (h ? hacc1[t][r] : hacc0[t][r]) + bv;
                }
            }
        }
    }
}

extern "C" void kernel_launch(void* const* d_in, const int* in_sizes, int n_in,
                              void* d_out, int out_size, void* d_ws, size_t ws_size,
                              hipStream_t stream) {
    const float* x    = (const float*)d_in[0];
    const int*   ei   = (const int*)d_in[1];
    const float* W1l  = (const float*)d_in[2];
    const float* b1   = (const float*)d_in[3];
    const float* W1r  = (const float*)d_in[4];
    const float* W2l  = (const float*)d_in[5];
    const float* b2   = (const float*)d_in[6];
    const float* W2r  = (const float*)d_in[7];
    const float* Wlin = (const float*)d_in[8];
    const float* blin = (const float*)d_in[9];
    float* out = (float*)d_out;

    const int N = NND, E = NED;
    const int* src = ei;
    const int* dst = ei + E;
    const int NB2 = HTN / 1024;  // 128 scan blocks

    char* w = (char*)d_ws;
    int*   histT  = (int*)w;               w += (size_t)HTN * 4;
    int*   sh     = (int*)w;               w += (size_t)HTN * 4;
    int*   psum   = (int*)w;               w += (size_t)NB2 * 4;
    int*   offs   = (int*)w;               w += (size_t)(N + 4) * 4;
    float* dinv   = (float*)w;             w += (size_t)N * 4;
    uint2* eS     = (uint2*)w;             w += (size_t)E * 8;
    int*   csr    = (int*)w;               w += (size_t)E * 4;
    unsigned short* p1  = (unsigned short*)w;  w += 256 * 128 * 2;
    unsigned short* p2  = (unsigned short*)w;  w += 256 * 128 * 2;
    unsigned short* ph  = (unsigned short*)w;  w += 128 * 64 * 2;
    unsigned short* xb  = (unsigned short*)w;  w += (size_t)N * 128 * 2;
    unsigned short* agg = (unsigned short*)w;  w += (size_t)N * 128 * 2;
    unsigned short* h1  = (unsigned short*)w;  w += (size_t)N * 128 * 2;

    // CSR build: zero global atomics
    k_hist_cast<<<NBLK, 256, 0, stream>>>(dst, histT, x, (unsigned int*)xb,
                                          W1l, W1r, W2l, W2r, Wlin, p1, p2, ph);
    g_scan1<<<NB2, 1024, 0, stream>>>(histT, psum, HTN);
    g_scan2<<<1, 128, 0, stream>>>(psum, NB2);
    g_scan3<<<NB2, 1024, 0, stream>>>(histT, psum, sh, HTN);
    k_scatter<<<NBLK, 256, 0, stream>>>(src, dst, sh, eS);
    k_bucket<<<NBUCK, 1024, 0, stream>>>(eS, sh, csr, offs, dinv, N);

    // layer 1: h1 = relu([agg|xb] @ [W1l;W1r] + b1)
    k_aggb<<<(N + 7) / 8, 256, 0, stream>>>((const uint4*)xb, offs, csr, dinv,
                                            (uint4*)agg, N);
    k_mfma<8, 8, true, true, false, false, true><<<(N + 127) / 128, 256, 0, stream>>>(
        agg, xb, p1, b1, nullptr, nullptr, nullptr, h1, N);

    // layer 2 + head fused
    k_aggb<<<(N + 7) / 8, 256, 0, stream>>>((const uint4*)h1, offs, csr, dinv,
                                            (uint4*)agg, N);
    k_mfma<8, 8, true, true, true, true, false><<<(N + 127) / 128, 256, 0, stream>>>(
        agg, h1, p2, b2, h1, ph, blin, out, N);
}